// Round 1
// baseline (334.357 us; speedup 1.0000x reference)
//
#include <hip/hip_runtime.h>
#include <math.h>

#define T_LEN 16384
#define DDIM  512
#define PADR  8
#define XROWS (T_LEN + 64)          // padded rows: 8 zero + 16384 + 56 zero
#define BM 128
#define BN 128
#define SLAB 160                    // staged slab rows (136 used)

typedef unsigned short u16;
typedef __attribute__((ext_vector_type(4))) float  f32x4;
typedef __attribute__((ext_vector_type(8))) __bf16 bf16x8;
typedef __attribute__((ext_vector_type(8))) unsigned short u16x8;

__device__ __forceinline__ float bf2f(u16 h) {
  return __uint_as_float(((unsigned)h) << 16);
}
__device__ __forceinline__ u16 f2bf(float f) {
  unsigned u = __float_as_uint(f);
  return (u16)((u + 0x7fffu + ((u >> 16) & 1u)) >> 16);   // RTN-even
}
__device__ __forceinline__ float gelu_exact(float v) {
  return 0.5f * v * (1.0f + erff(v * 0.7071067811865475f));
}
__device__ __forceinline__ void gll16(const void* g, void* l) {
  __builtin_amdgcn_global_load_lds(
      (const __attribute__((address_space(1))) void*)g,
      (__attribute__((address_space(3))) void*)l, 16, 0, 0);
}

// cos(pi*m/4), indexed by (j*k)&7
__device__ const float g_C[8] = {1.0f, 0.70710678118654752f, 0.0f, -0.70710678118654752f,
                                 -1.0f, -0.70710678118654752f, 0.0f, 0.70710678118654752f};

// ---------------- fold W' = C^T (x) W, store transposed bf16: Wt[n][j*512+d] ----------------
__global__ __launch_bounds__(256) void k_fold(const float* __restrict__ W, u16* __restrict__ wt) {
  __shared__ u16 tile[64][65];
  int kd0 = blockIdx.x * 64;            // 0..4032  (j*512 + d block)
  int n0  = blockIdx.y * 64;
  int j   = kd0 >> 9;
  int d0  = kd0 & 511;
  int t   = threadIdx.x;
  int nl  = t & 63;
  int dseg = t >> 6;
  for (int s = 0; s < 16; ++s) {
    int dl = dseg * 16 + s;
    float acc = 0.f;
#pragma unroll
    for (int k = 0; k < 8; ++k)
      acc += g_C[(j * k) & 7] * W[(size_t)(k * 512 + d0 + dl) * 512 + n0 + nl];
    tile[dl][nl] = f2bf(acc);
  }
  __syncthreads();
  int r  = t >> 2;                       // 0..63 (n within tile)
  int c0 = (t & 3) * 16;                 // 0..48 (kd within tile)
  u16* dst = wt + (size_t)(n0 + r) * 4096 + kd0 + c0;
  u16x8 v0, v1;
#pragma unroll
  for (int u = 0; u < 8; ++u) { v0[u] = tile[c0 + u][r]; v1[u] = tile[c0 + 8 + u][r]; }
  *(u16x8*)dst = v0;
  *(u16x8*)(dst + 8) = v1;
}

// ---------------- x -> zero-padded bf16 xpad[XROWS][512] ----------------
__global__ __launch_bounds__(256) void k_pad(const float* __restrict__ x, u16* __restrict__ xpad) {
  long t = (long)blockIdx.x * 256 + threadIdx.x;
  long base = t * 8;                     // element index into xpad flat
  u16x8 o;
  const long lo = (long)PADR * 512, hi = (long)(PADR + T_LEN) * 512;
  if (base >= lo && base < hi) {
    f32x4 a = *(const f32x4*)(x + (base - lo));
    f32x4 b = *(const f32x4*)(x + (base - lo) + 4);
#pragma unroll
    for (int u = 0; u < 4; ++u) { o[u] = f2bf(a[u]); o[u + 4] = f2bf(b[u]); }
  } else {
#pragma unroll
    for (int u = 0; u < 8; ++u) o[u] = 0;
  }
  *(u16x8*)&xpad[base] = o;
}

// ---------------- coarse[i] = x[max(0,i-3)] ----------------
__global__ __launch_bounds__(256) void k_coarse(const float* __restrict__ x, float* __restrict__ outc) {
  long t = (long)blockIdx.x * 256 + threadIdx.x;
  long idx = t * 4;
  int i = (int)(idx >> 9);
  int d = (int)(idx & 511);
  int src = (i >= 3) ? (i - 3) : 0;
  *(f32x4*)&outc[idx] = *(const f32x4*)&x[(long)src * 512 + d];
}

// ---------------- main conv-GEMM: fine = gelu(sum_j x[i-3+j] @ W'_j + b) ----------------
__global__ __launch_bounds__(256, 2) void k_gemm(const u16* __restrict__ xpad,
                                                 const u16* __restrict__ wt,
                                                 const float* __restrict__ bias,
                                                 float* __restrict__ fine) {
  __shared__ __align__(16) u16 As[SLAB * 64];   // [slab_row][64]
  __shared__ __align__(16) u16 Bs[BN * 64];     // [n][64]
  int n0 = blockIdx.x * BN;
  int i0 = blockIdx.y * BM;
  int t = threadIdx.x;
  int lane = t & 63;
  int wid = t >> 6;
  int wr = wid >> 1, wc = wid & 1;
  f32x4 acc[4][4] = {};

  for (int kc = 0; kc < 8; ++kc) {
    // stage A slab: rows r hold xpad row (i0+5+r) = x row (i0-3+r), cols kc*64..+64
#pragma unroll
    for (int p = 0; p < 5; ++p) {
      int off = p * 4096 + t * 16;                 // byte offset in As
      int row = off >> 7;
      int slot = (off >> 4) & 7;
      const u16* src = xpad + (size_t)(i0 + 5 + row) * 512 + kc * 64 + slot * 8;
      gll16(src, (char*)As + off);
    }
    for (int jo = 0; jo < 8; ++jo) {
      // stage B: Bs[n][k] <- Wt[n0+n][jo*512 + kc*64 + k]
#pragma unroll
      for (int p = 0; p < 4; ++p) {
        int off = p * 4096 + t * 16;
        int nr = off >> 7;
        int slot = (off >> 4) & 7;
        const u16* src = wt + (size_t)(n0 + nr) * 4096 + jo * 512 + kc * 64 + slot * 8;
        gll16(src, (char*)Bs + off);
      }
      __syncthreads();
      int arow = wr * 64 + (lane & 15) + jo;       // slab row of A fragment
      int brow = wc * 64 + (lane & 15);
      int kb = (lane >> 4) * 8;
#pragma unroll
      for (int ks = 0; ks < 2; ++ks) {
        bf16x8 a[4], b[4];
#pragma unroll
        for (int mi = 0; mi < 4; ++mi)
          a[mi] = *(const bf16x8*)&As[(arow + mi * 16) * 64 + ks * 32 + kb];
#pragma unroll
        for (int ni = 0; ni < 4; ++ni)
          b[ni] = *(const bf16x8*)&Bs[(brow + ni * 16) * 64 + ks * 32 + kb];
#pragma unroll
        for (int mi = 0; mi < 4; ++mi)
#pragma unroll
          for (int ni = 0; ni < 4; ++ni)
            acc[mi][ni] = __builtin_amdgcn_mfma_f32_16x16x32_bf16(a[mi], b[ni], acc[mi][ni], 0, 0, 0);
      }
      __syncthreads();
    }
  }
  // epilogue: bias + exact GELU, f32 stores
#pragma unroll
  for (int ni = 0; ni < 4; ++ni) {
    int n = n0 + wc * 64 + ni * 16 + (lane & 15);
    float bv = bias[n];
#pragma unroll
    for (int mi = 0; mi < 4; ++mi) {
      int ib = i0 + wr * 64 + mi * 16 + ((lane >> 4) * 4);
      f32x4 v = acc[mi][ni];
#pragma unroll
      for (int e = 0; e < 4; ++e)
        fine[(size_t)(ib + e) * 512 + n] = gelu_exact(v[e] + bv);
    }
  }
}

// ---------------- left-edge fixup: rows 0..2 use absolute-position weights ----------------
__global__ __launch_bounds__(512) void k_edge(const u16* __restrict__ xpad, const u16* __restrict__ wt,
                                              const float* __restrict__ bias, float* __restrict__ fine) {
  int i = blockIdx.x;        // 0..2
  int n = threadIdx.x;       // 0..511
  int len = (i + 5) * 512;   // window covers x[0..i+4]
  const u16* xr = xpad + PADR * 512;
  const u16* wr = wt + (size_t)n * 4096;
  float s = bias[n];
  for (int k = 0; k < len; k += 8) {
    u16x8 xv = *(const u16x8*)&xr[k];
    u16x8 wv = *(const u16x8*)&wr[k];
#pragma unroll
    for (int u = 0; u < 8; ++u) s += bf2f(xv[u]) * bf2f(wv[u]);
  }
  fine[(size_t)i * 512 + n] = gelu_exact(s);
}

extern "C" void kernel_launch(void* const* d_in, const int* in_sizes, int n_in,
                              void* d_out, int out_size, void* d_ws, size_t ws_size,
                              hipStream_t stream) {
  const float* x = (const float*)d_in[0];    // [1,16384,512]
  const float* W = (const float*)d_in[1];    // [4096,512]
  const float* b = (const float*)d_in[2];    // [512]
  float* outc = (float*)d_out;                         // coarse [16384,512]
  float* outf = (float*)d_out + (size_t)T_LEN * DDIM;  // fine   [16384,512]

  u16* xpad = (u16*)d_ws;                                        // XROWS*512*2 = 16,842,752 B
  u16* wt   = (u16*)((char*)d_ws + (size_t)XROWS * 512 * 2);     // 512*4096*2  =  4,194,304 B

  k_fold  <<<dim3(64, 8),  256, 0, stream>>>(W, wt);
  k_pad   <<<dim3(4112),   256, 0, stream>>>(x, xpad);
  k_coarse<<<dim3(8192),   256, 0, stream>>>(x, outc);
  k_gemm  <<<dim3(4, 128), 256, 0, stream>>>(xpad, wt, b, outf);
  k_edge  <<<dim3(3),      512, 0, stream>>>(xpad, wt, b, outf);
}

// Round 2
// 212.285 us; speedup vs baseline: 1.5750x; 1.5750x over previous
//
#include <hip/hip_runtime.h>
#include <math.h>

#define T_LEN 16384
#define DDIM  512
#define PADR  8
#define XROWS (T_LEN + 64)          // padded rows: 8 zero + 16384 + 56 zero
#define BM 128
#define BN 128
#define SLAB 160                    // staged slab rows (136 used)

typedef unsigned short u16;
typedef __attribute__((ext_vector_type(4))) float  f32x4;
typedef __attribute__((ext_vector_type(8))) __bf16 bf16x8;
typedef __attribute__((ext_vector_type(8))) unsigned short u16x8;
typedef __attribute__((ext_vector_type(4))) unsigned short u16x4;

__device__ __forceinline__ float bf2f(u16 h) {
  return __uint_as_float(((unsigned)h) << 16);
}
__device__ __forceinline__ u16 f2bf(float f) {
  unsigned u = __float_as_uint(f);
  return (u16)((u + 0x7fffu + ((u >> 16) & 1u)) >> 16);   // RTN-even
}
__device__ __forceinline__ float gelu_exact(float v) {
  return 0.5f * v * (1.0f + erff(v * 0.7071067811865475f));
}
__device__ __forceinline__ void gll16(const void* g, void* l) {
  __builtin_amdgcn_global_load_lds(
      (const __attribute__((address_space(1))) void*)g,
      (__attribute__((address_space(3))) void*)l, 16, 0, 0);
}

// cos(pi*m/4), indexed by (j*k)&7
__device__ const float g_C[8] = {1.0f, 0.70710678118654752f, 0.0f, -0.70710678118654752f,
                                 -1.0f, -0.70710678118654752f, 0.0f, 0.70710678118654752f};

// ---------------- fold W' = C^T (x) W, store transposed bf16: Wt[n][j*512+d] ----------------
__global__ __launch_bounds__(256) void k_fold(const float* __restrict__ W, u16* __restrict__ wt) {
  __shared__ u16 tile[64][65];
  int kd0 = blockIdx.x * 64;            // 0..4032  (j*512 + d block)
  int n0  = blockIdx.y * 64;
  int j   = kd0 >> 9;
  int d0  = kd0 & 511;
  int t   = threadIdx.x;
  int nl  = t & 63;
  int dseg = t >> 6;
  for (int s = 0; s < 16; ++s) {
    int dl = dseg * 16 + s;
    float acc = 0.f;
#pragma unroll
    for (int k = 0; k < 8; ++k)
      acc += g_C[(j * k) & 7] * W[(size_t)(k * 512 + d0 + dl) * 512 + n0 + nl];
    tile[dl][nl] = f2bf(acc);
  }
  __syncthreads();
  int r  = t >> 2;                       // 0..63 (n within tile)
  int c0 = (t & 3) * 16;                 // 0..48 (kd within tile)
  u16* dst = wt + (size_t)(n0 + r) * 4096 + kd0 + c0;
  u16x8 v0, v1;
#pragma unroll
  for (int u = 0; u < 8; ++u) { v0[u] = tile[c0 + u][r]; v1[u] = tile[c0 + 8 + u][r]; }
  *(u16x8*)dst = v0;
  *(u16x8*)(dst + 8) = v1;
}

// ---------------- fused: x -> bf16 xpad (zero-padded) AND coarse[i]=x[max(0,i-3)] ----------------
__global__ __launch_bounds__(256) void k_prep(const float* __restrict__ x,
                                              u16* __restrict__ xpad,
                                              float* __restrict__ outc) {
  int bid = blockIdx.x;
  if (bid >= 8192) {
    // zero the pad rows: 8 front rows (4096 u16) + 56 tail rows (28672 u16)
    int z = (bid - 8192) * 256 + threadIdx.x;     // 0..4095, 8 u16 each
    u16x8 zero = {};
    if (z < 512) {
      *(u16x8*)&xpad[(size_t)z * 8] = zero;
    } else {
      size_t zz = (size_t)(z - 512);
      *(u16x8*)&xpad[(size_t)(PADR + T_LEN) * 512 + zz * 8] = zero;
    }
    return;
  }
  long t = (long)bid * 256 + threadIdx.x;
  long idx = t * 4;                                // element index into x flat
  int i = (int)(idx >> 9);
  int d = (int)(idx & 511);
  f32x4 v = *(const f32x4*)&x[idx];
  u16x4 o;
#pragma unroll
  for (int u = 0; u < 4; ++u) o[u] = f2bf(v[u]);
  *(u16x4*)&xpad[(size_t)(i + PADR) * 512 + d] = o;
  if (i <= T_LEN - 4) *(f32x4*)&outc[(size_t)(i + 3) * 512 + d] = v;
  if (i == 0) {
    *(f32x4*)&outc[(size_t)0 * 512 + d] = v;
    *(f32x4*)&outc[(size_t)1 * 512 + d] = v;
    *(f32x4*)&outc[(size_t)2 * 512 + d] = v;
  }
}

// ---------------- main conv-GEMM: fine = gelu(sum_j x[i-3+j] @ W'_j + b) ----------------
__global__ __launch_bounds__(256, 2) void k_gemm(const u16* __restrict__ xpad,
                                                 const u16* __restrict__ wt,
                                                 const float* __restrict__ bias,
                                                 float* __restrict__ fine) {
  __shared__ __align__(16) u16 As[SLAB * 64];   // [slab_row][64]
  __shared__ __align__(16) u16 Bs[BN * 64];     // [n][64]
  int n0 = blockIdx.x * BN;
  int i0 = blockIdx.y * BM;
  int t = threadIdx.x;
  int lane = t & 63;
  int wid = t >> 6;
  int wr = wid >> 1, wc = wid & 1;
  f32x4 acc[4][4] = {};

  for (int kc = 0; kc < 8; ++kc) {
    // stage A slab: rows r hold xpad row (i0+5+r) = x row (i0-3+r), cols kc*64..+64
#pragma unroll
    for (int p = 0; p < 5; ++p) {
      int off = p * 4096 + t * 16;                 // byte offset in As
      int row = off >> 7;
      int slot = (off >> 4) & 7;
      const u16* src = xpad + (size_t)(i0 + 5 + row) * 512 + kc * 64 + slot * 8;
      gll16(src, (char*)As + off);
    }
    for (int jo = 0; jo < 8; ++jo) {
      // stage B: Bs[n][k] <- Wt[n0+n][jo*512 + kc*64 + k]
#pragma unroll
      for (int p = 0; p < 4; ++p) {
        int off = p * 4096 + t * 16;
        int nr = off >> 7;
        int slot = (off >> 4) & 7;
        const u16* src = wt + (size_t)(n0 + nr) * 4096 + jo * 512 + kc * 64 + slot * 8;
        gll16(src, (char*)Bs + off);
      }
      __syncthreads();
      int arow = wr * 64 + (lane & 15) + jo;       // slab row of A fragment
      int brow = wc * 64 + (lane & 15);
      int kb = (lane >> 4) * 8;
#pragma unroll
      for (int ks = 0; ks < 2; ++ks) {
        bf16x8 a[4], b[4];
#pragma unroll
        for (int mi = 0; mi < 4; ++mi)
          a[mi] = *(const bf16x8*)&As[(arow + mi * 16) * 64 + ks * 32 + kb];
#pragma unroll
        for (int ni = 0; ni < 4; ++ni)
          b[ni] = *(const bf16x8*)&Bs[(brow + ni * 16) * 64 + ks * 32 + kb];
#pragma unroll
        for (int mi = 0; mi < 4; ++mi)
#pragma unroll
          for (int ni = 0; ni < 4; ++ni)
            acc[mi][ni] = __builtin_amdgcn_mfma_f32_16x16x32_bf16(a[mi], b[ni], acc[mi][ni], 0, 0, 0);
      }
      __syncthreads();
    }
  }
  // epilogue: bias + exact GELU, f32 stores
#pragma unroll
  for (int ni = 0; ni < 4; ++ni) {
    int n = n0 + wc * 64 + ni * 16 + (lane & 15);
    float bv = bias[n];
#pragma unroll
    for (int mi = 0; mi < 4; ++mi) {
      int ib = i0 + wr * 64 + mi * 16 + ((lane >> 4) * 4);
      f32x4 v = acc[mi][ni];
#pragma unroll
      for (int e = 0; e < 4; ++e)
        fine[(size_t)(ib + e) * 512 + n] = gelu_exact(v[e] + bv);
    }
  }
}

// ---------------- left-edge fixup: one wave per (i,n), coalesced + butterfly reduce ----------------
__global__ __launch_bounds__(256) void k_edge(const u16* __restrict__ xpad, const u16* __restrict__ wt,
                                              const float* __restrict__ bias, float* __restrict__ fine) {
  int o = blockIdx.x * 4 + (threadIdx.x >> 6);   // 0..1535 output id
  int lane = threadIdx.x & 63;
  int i = o >> 9;            // 0..2
  int n = o & 511;
  int len = (i + 5) * 512;   // window covers x[0..i+4]
  const u16* xr = xpad + PADR * 512;
  const u16* wrow = wt + (size_t)n * 4096;
  float s = 0.f;
#pragma unroll
  for (int m = 0; m < 7; ++m) {
    int k = (m * 64 + lane) * 8;
    if (k < len) {
      u16x8 xv = *(const u16x8*)&xr[k];
      u16x8 wv = *(const u16x8*)&wrow[k];
#pragma unroll
      for (int u = 0; u < 8; ++u) s += bf2f(xv[u]) * bf2f(wv[u]);
    }
  }
#pragma unroll
  for (int off = 32; off; off >>= 1) s += __shfl_xor(s, off);
  if (lane == 0) fine[(size_t)i * 512 + n] = gelu_exact(s + bias[n]);
}

extern "C" void kernel_launch(void* const* d_in, const int* in_sizes, int n_in,
                              void* d_out, int out_size, void* d_ws, size_t ws_size,
                              hipStream_t stream) {
  const float* x = (const float*)d_in[0];    // [1,16384,512]
  const float* W = (const float*)d_in[1];    // [4096,512]
  const float* b = (const float*)d_in[2];    // [512]
  float* outc = (float*)d_out;                         // coarse [16384,512]
  float* outf = (float*)d_out + (size_t)T_LEN * DDIM;  // fine   [16384,512]

  u16* xpad = (u16*)d_ws;                                        // XROWS*512*2 = 16,842,752 B
  u16* wt   = (u16*)((char*)d_ws + (size_t)XROWS * 512 * 2);     // 512*4096*2  =  4,194,304 B

  k_fold <<<dim3(64, 8),   256, 0, stream>>>(W, wt);
  k_prep <<<dim3(8208),    256, 0, stream>>>(x, xpad, outc);
  k_gemm <<<dim3(4, 128),  256, 0, stream>>>(xpad, wt, b, outf);
  k_edge <<<dim3(384),     256, 0, stream>>>(xpad, wt, b, outf);
}

// Round 3
// 189.422 us; speedup vs baseline: 1.7651x; 1.1207x over previous
//
#include <hip/hip_runtime.h>
#include <math.h>

#define T_LEN 16384
#define DDIM  512
#define PADR  8
#define XROWS (T_LEN + 64)          // padded rows: 8 zero + 16384 + 56 zero
#define BM 256
#define BN 128
#define AELEMS 16384                // 256*64 u16
#define BELEMS 8192                 // 128*64 u16
#define BUFELEMS (AELEMS + BELEMS)  // 24576 u16 = 48 KiB

typedef unsigned short u16;
typedef __attribute__((ext_vector_type(4))) float  f32x4;
typedef __attribute__((ext_vector_type(8))) __bf16 bf16x8;
typedef __attribute__((ext_vector_type(8))) unsigned short u16x8;
typedef __attribute__((ext_vector_type(4))) unsigned short u16x4;

__device__ __forceinline__ float bf2f(u16 h) {
  return __uint_as_float(((unsigned)h) << 16);
}
__device__ __forceinline__ u16 f2bf(float f) {
  unsigned u = __float_as_uint(f);
  return (u16)((u + 0x7fffu + ((u >> 16) & 1u)) >> 16);   // RTN-even
}
__device__ __forceinline__ float gelu_exact(float v) {
  return 0.5f * v * (1.0f + erff(v * 0.7071067811865475f));
}
__device__ __forceinline__ void gll16(const void* g, void* l) {
  __builtin_amdgcn_global_load_lds(
      (const __attribute__((address_space(1))) void*)g,
      (__attribute__((address_space(3))) void*)l, 16, 0, 0);
}

// cos(pi*m/4), indexed by (j*k)&7
__device__ const float g_C[8] = {1.0f, 0.70710678118654752f, 0.0f, -0.70710678118654752f,
                                 -1.0f, -0.70710678118654752f, 0.0f, 0.70710678118654752f};

// ---------------- fold W' = C^T (x) W, store transposed bf16: Wt[n][j*512+d] ----------------
__global__ __launch_bounds__(256) void k_fold(const float* __restrict__ W, u16* __restrict__ wt) {
  __shared__ u16 tile[64][65];
  int kd0 = blockIdx.x * 64;            // 0..4032  (j*512 + d block)
  int n0  = blockIdx.y * 64;
  int j   = kd0 >> 9;
  int d0  = kd0 & 511;
  int t   = threadIdx.x;
  int nl  = t & 63;
  int dseg = t >> 6;
  for (int s = 0; s < 16; ++s) {
    int dl = dseg * 16 + s;
    float acc = 0.f;
#pragma unroll
    for (int k = 0; k < 8; ++k)
      acc += g_C[(j * k) & 7] * W[(size_t)(k * 512 + d0 + dl) * 512 + n0 + nl];
    tile[dl][nl] = f2bf(acc);
  }
  __syncthreads();
  int r  = t >> 2;                       // 0..63 (n within tile)
  int c0 = (t & 3) * 16;                 // 0..48 (kd within tile)
  u16* dst = wt + (size_t)(n0 + r) * 4096 + kd0 + c0;
  u16x8 v0, v1;
#pragma unroll
  for (int u = 0; u < 8; ++u) { v0[u] = tile[c0 + u][r]; v1[u] = tile[c0 + 8 + u][r]; }
  *(u16x8*)dst = v0;
  *(u16x8*)(dst + 8) = v1;
}

// ---------------- fused: x -> bf16 xpad (zero-padded) AND coarse[i]=x[max(0,i-3)] ----------------
__global__ __launch_bounds__(256) void k_prep(const float* __restrict__ x,
                                              u16* __restrict__ xpad,
                                              float* __restrict__ outc) {
  int bid = blockIdx.x;
  if (bid >= 8192) {
    int z = (bid - 8192) * 256 + threadIdx.x;     // 0..4095, 8 u16 each
    u16x8 zero = {};
    if (z < 512) {
      *(u16x8*)&xpad[(size_t)z * 8] = zero;
    } else {
      size_t zz = (size_t)(z - 512);
      *(u16x8*)&xpad[(size_t)(PADR + T_LEN) * 512 + zz * 8] = zero;
    }
    return;
  }
  long t = (long)bid * 256 + threadIdx.x;
  long idx = t * 4;                                // element index into x flat
  int i = (int)(idx >> 9);
  int d = (int)(idx & 511);
  f32x4 v = *(const f32x4*)&x[idx];
  u16x4 o;
#pragma unroll
  for (int u = 0; u < 4; ++u) o[u] = f2bf(v[u]);
  *(u16x4*)&xpad[(size_t)(i + PADR) * 512 + d] = o;
  if (i <= T_LEN - 4) *(f32x4*)&outc[(size_t)(i + 3) * 512 + d] = v;
  if (i == 0) {
    *(f32x4*)&outc[(size_t)0 * 512 + d] = v;
    *(f32x4*)&outc[(size_t)1 * 512 + d] = v;
    *(f32x4*)&outc[(size_t)2 * 512 + d] = v;
  }
}

// ---------------- 8-phase pipelined conv-GEMM ----------------
// A[i][k] = xpad_flat[(i+5)*512 + k]  (im2col == overlapping-row view), K=4096.
// T2 swizzle: LDS[row][slot_phys] holds global[row][slot_phys ^ (row&7)] (16B slots).
// global_load_lds dest stays linear; source pre-swizzled; ds_read applies same XOR.

__device__ __forceinline__ void stageA(const u16* __restrict__ xpad, u16* dstA,
                                       int i0, int k0, int tid, int p) {
  int c = p * 512 + tid;                 // chunk id: row = c>>3, phys slot = c&7
  int r = c >> 3;
  int sl = (c & 7) ^ (r & 7);
  gll16(xpad + (size_t)(i0 + 5 + r) * 512 + k0 + sl * 8, dstA + (size_t)c * 8);
}
__device__ __forceinline__ void stageB(const u16* __restrict__ wt, u16* dstB,
                                       int n0, int k0, int tid, int p) {
  int c = p * 512 + tid;
  int r = c >> 3;
  int sl = (c & 7) ^ (r & 7);
  gll16(wt + (size_t)(n0 + r) * 4096 + k0 + sl * 8, dstB + (size_t)c * 8);
}
__device__ __forceinline__ bf16x8 rdfrag(const u16* base, int row, int slot_log) {
  int sl = slot_log ^ (row & 7);
  return *(const bf16x8*)(base + row * 64 + sl * 8);
}

#define MFMA __builtin_amdgcn_mfma_f32_16x16x32_bf16

// MODE 0: stage t+2 + tail vmcnt(6); MODE 1: no stage + tail vmcnt(0); MODE 2: no stage, no tail wait
template<int MODE>
__device__ __forceinline__ void kstep(const u16* __restrict__ xpad, const u16* __restrict__ wt,
                                      const u16* Ab, const u16* Bb, u16* An, u16* Bn,
                                      int i0, int n0, int k0n, int tid, int lane, int wr, int wc,
                                      f32x4 (&acc)[8][2]) {
  int slg = lane >> 4;                   // 0..3
  int br = wc * 32 + (lane & 15);
  bf16x8 b00 = rdfrag(Bb, br, slg);          // n=0, ks=0
  bf16x8 b01 = rdfrag(Bb, br, slg + 4);      // n=0, ks=1
  bf16x8 b10 = rdfrag(Bb, br + 16, slg);     // n=1, ks=0
  bf16x8 b11 = rdfrag(Bb, br + 16, slg + 4); // n=1, ks=1

#define PHASE(MQ, STG, TAIL)                                                  \
  {                                                                           \
    int ar = wr * 128 + (MQ) * 32 + (lane & 15);                              \
    bf16x8 a00 = rdfrag(Ab, ar, slg);                                         \
    bf16x8 a01 = rdfrag(Ab, ar, slg + 4);                                     \
    bf16x8 a10 = rdfrag(Ab, ar + 16, slg);                                    \
    bf16x8 a11 = rdfrag(Ab, ar + 16, slg + 4);                                \
    STG                                                                       \
    __builtin_amdgcn_s_barrier();                                             \
    asm volatile("s_waitcnt lgkmcnt(0)" ::: "memory");                        \
    __builtin_amdgcn_sched_barrier(0);                                        \
    __builtin_amdgcn_s_setprio(1);                                            \
    acc[(MQ)*2][0]   = MFMA(a00, b00, acc[(MQ)*2][0],   0, 0, 0);             \
    acc[(MQ)*2][0]   = MFMA(a01, b01, acc[(MQ)*2][0],   0, 0, 0);             \
    acc[(MQ)*2][1]   = MFMA(a00, b10, acc[(MQ)*2][1],   0, 0, 0);             \
    acc[(MQ)*2][1]   = MFMA(a01, b11, acc[(MQ)*2][1],   0, 0, 0);             \
    acc[(MQ)*2+1][0] = MFMA(a10, b00, acc[(MQ)*2+1][0], 0, 0, 0);             \
    acc[(MQ)*2+1][0] = MFMA(a11, b01, acc[(MQ)*2+1][0], 0, 0, 0);             \
    acc[(MQ)*2+1][1] = MFMA(a10, b10, acc[(MQ)*2+1][1], 0, 0, 0);             \
    acc[(MQ)*2+1][1] = MFMA(a11, b11, acc[(MQ)*2+1][1], 0, 0, 0);             \
    __builtin_amdgcn_s_setprio(0);                                            \
    TAIL                                                                      \
    __builtin_amdgcn_s_barrier();                                             \
  }

  if constexpr (MODE == 0) {
    PHASE(0, { stageA(xpad, An, i0, k0n, tid, 0); stageA(xpad, An, i0, k0n, tid, 1); }, {})
    PHASE(1, { stageA(xpad, An, i0, k0n, tid, 2); stageA(xpad, An, i0, k0n, tid, 3); }, {})
    PHASE(2, { stageB(wt, Bn, n0, k0n, tid, 0);   stageB(wt, Bn, n0, k0n, tid, 1);   }, {})
    PHASE(3, {}, { asm volatile("s_waitcnt vmcnt(6)" ::: "memory"); })
  } else if constexpr (MODE == 1) {
    PHASE(0, {}, {})
    PHASE(1, {}, {})
    PHASE(2, {}, {})
    PHASE(3, {}, { asm volatile("s_waitcnt vmcnt(0)" ::: "memory"); })
  } else {
    PHASE(0, {}, {})
    PHASE(1, {}, {})
    PHASE(2, {}, {})
    PHASE(3, {}, {})
  }
#undef PHASE
}

__global__ __launch_bounds__(512, 2) void k_gemm(const u16* __restrict__ xpad,
                                                 const u16* __restrict__ wt,
                                                 const float* __restrict__ bias,
                                                 float* __restrict__ fine) {
  __shared__ __align__(16) u16 lds[3][BUFELEMS];   // 144 KiB, 3-deep pipeline
  // T1: XCD-contiguous block mapping (256 % 8 == 0 -> simple bijective swizzle)
  int orig = blockIdx.x;
  int id = (orig & 7) * 32 + (orig >> 3);
  int n0 = (id & 3) * BN;           // 4 n-blocks fastest: same-XCD ids share A panels
  int i0 = (id >> 2) * BM;
  int tid = threadIdx.x;
  int lane = tid & 63;
  int wid = tid >> 6;
  int wr = wid >> 2, wc = wid & 3;  // 2 x 4 wave grid; per-wave 128x32 output
  f32x4 acc[8][2] = {};

  // prologue: stage K-steps 0 and 1 (6 loads each)
#pragma unroll
  for (int p = 0; p < 4; ++p) stageA(xpad, &lds[0][0], i0, 0, tid, p);
#pragma unroll
  for (int p = 0; p < 2; ++p) stageB(wt, &lds[0][AELEMS], n0, 0, tid, p);
#pragma unroll
  for (int p = 0; p < 4; ++p) stageA(xpad, &lds[1][0], i0, 64, tid, p);
#pragma unroll
  for (int p = 0; p < 2; ++p) stageB(wt, &lds[1][AELEMS], n0, 64, tid, p);
  asm volatile("s_waitcnt vmcnt(6)" ::: "memory");   // step 0 landed; step 1 in flight
  __builtin_amdgcn_s_barrier();

  int b = 0;
  for (int t = 0; t < 62; ++t) {
    int bs = b + 2; if (bs >= 3) bs -= 3;
    kstep<0>(xpad, wt, &lds[b][0], &lds[b][AELEMS], &lds[bs][0], &lds[bs][AELEMS],
             i0, n0, (t + 2) * 64, tid, lane, wr, wc, acc);
    if (++b == 3) b = 0;
  }
  kstep<1>(xpad, wt, &lds[b][0], &lds[b][AELEMS], nullptr, nullptr,
           i0, n0, 0, tid, lane, wr, wc, acc);
  if (++b == 3) b = 0;
  kstep<2>(xpad, wt, &lds[b][0], &lds[b][AELEMS], nullptr, nullptr,
           i0, n0, 0, tid, lane, wr, wc, acc);

  // epilogue: bias + exact GELU
#pragma unroll
  for (int n = 0; n < 2; ++n) {
    int col = n0 + wc * 32 + n * 16 + (lane & 15);
    float bv = bias[col];
#pragma unroll
    for (int m = 0; m < 8; ++m) {
      int row = i0 + wr * 128 + m * 16 + ((lane >> 4) * 4);
      f32x4 v = acc[m][n];
#pragma unroll
      for (int e = 0; e < 4; ++e)
        fine[(size_t)(row + e) * 512 + col] = gelu_exact(v[e] + bv);
    }
  }
}

// ---------------- left-edge fixup: one wave per (i,n), coalesced + butterfly reduce ----------------
__global__ __launch_bounds__(256) void k_edge(const u16* __restrict__ xpad, const u16* __restrict__ wt,
                                              const float* __restrict__ bias, float* __restrict__ fine) {
  int o = blockIdx.x * 4 + (threadIdx.x >> 6);   // 0..1535 output id
  int lane = threadIdx.x & 63;
  int i = o >> 9;            // 0..2
  int n = o & 511;
  int len = (i + 5) * 512;   // window covers x[0..i+4]
  const u16* xr = xpad + PADR * 512;
  const u16* wrow = wt + (size_t)n * 4096;
  float s = 0.f;
#pragma unroll
  for (int m = 0; m < 7; ++m) {
    int k = (m * 64 + lane) * 8;
    if (k < len) {
      u16x8 xv = *(const u16x8*)&xr[k];
      u16x8 wv = *(const u16x8*)&wrow[k];
#pragma unroll
      for (int u = 0; u < 8; ++u) s += bf2f(xv[u]) * bf2f(wv[u]);
    }
  }
#pragma unroll
  for (int off = 32; off; off >>= 1) s += __shfl_xor(s, off);
  if (lane == 0) fine[(size_t)i * 512 + n] = gelu_exact(s + bias[n]);
}

extern "C" void kernel_launch(void* const* d_in, const int* in_sizes, int n_in,
                              void* d_out, int out_size, void* d_ws, size_t ws_size,
                              hipStream_t stream) {
  const float* x = (const float*)d_in[0];    // [1,16384,512]
  const float* W = (const float*)d_in[1];    // [4096,512]
  const float* b = (const float*)d_in[2];    // [512]
  float* outc = (float*)d_out;                         // coarse [16384,512]
  float* outf = (float*)d_out + (size_t)T_LEN * DDIM;  // fine   [16384,512]

  u16* xpad = (u16*)d_ws;                                        // XROWS*512*2 = 16,842,752 B
  u16* wt   = (u16*)((char*)d_ws + (size_t)XROWS * 512 * 2);     // 512*4096*2  =  4,194,304 B

  k_fold <<<dim3(64, 8),   256, 0, stream>>>(W, wt);
  k_prep <<<dim3(8208),    256, 0, stream>>>(x, xpad, outc);
  k_gemm <<<dim3(256),     512, 0, stream>>>(xpad, wt, b, outf);
  k_edge <<<dim3(384),     256, 0, stream>>>(xpad, wt, b, outf);
}

// Round 4
// 176.638 us; speedup vs baseline: 1.8929x; 1.0724x over previous
//
#include <hip/hip_runtime.h>
#include <math.h>

#define T_LEN 16384
#define DDIM  512
#define PADR  8
#define XROWS (T_LEN + 64)          // padded rows: 8 zero + 16384 + 56 zero
#define BM 256
#define BN 128
#define SLABR 320                   // A slab rows per kc (263 used, 5 full stage passes)
#define AELEMS (SLABR * 64)         // 20480 u16 = 40 KiB
#define BELEMS 8192                 // 128*64 u16 = 16 KiB

typedef unsigned short u16;
typedef __attribute__((ext_vector_type(4))) float  f32x4;
typedef __attribute__((ext_vector_type(8))) __bf16 bf16x8;
typedef __attribute__((ext_vector_type(8))) unsigned short u16x8;
typedef __attribute__((ext_vector_type(4))) unsigned short u16x4;

__device__ __forceinline__ float bf2f(u16 h) {
  return __uint_as_float(((unsigned)h) << 16);
}
__device__ __forceinline__ u16 f2bf(float f) {
  unsigned u = __float_as_uint(f);
  return (u16)((u + 0x7fffu + ((u >> 16) & 1u)) >> 16);   // RTN-even
}
__device__ __forceinline__ float gelu_exact(float v) {
  return 0.5f * v * (1.0f + erff(v * 0.7071067811865475f));
}
__device__ __forceinline__ void gll16(const void* g, void* l) {
  __builtin_amdgcn_global_load_lds(
      (const __attribute__((address_space(1))) void*)g,
      (__attribute__((address_space(3))) void*)l, 16, 0, 0);
}

// cos(pi*m/4), indexed by (j*k)&7
__device__ const float g_C[8] = {1.0f, 0.70710678118654752f, 0.0f, -0.70710678118654752f,
                                 -1.0f, -0.70710678118654752f, 0.0f, 0.70710678118654752f};

// ---------------- fold W' = C^T (x) W, store transposed bf16: Wt[n][j*512+d] ----------------
__global__ __launch_bounds__(256) void k_fold(const float* __restrict__ W, u16* __restrict__ wt) {
  __shared__ u16 tile[64][65];
  int kd0 = blockIdx.x * 64;            // 0..4032  (j*512 + d block)
  int n0  = blockIdx.y * 64;
  int j   = kd0 >> 9;
  int d0  = kd0 & 511;
  int t   = threadIdx.x;
  int nl  = t & 63;
  int dseg = t >> 6;
  for (int s = 0; s < 16; ++s) {
    int dl = dseg * 16 + s;
    float acc = 0.f;
#pragma unroll
    for (int k = 0; k < 8; ++k)
      acc += g_C[(j * k) & 7] * W[(size_t)(k * 512 + d0 + dl) * 512 + n0 + nl];
    tile[dl][nl] = f2bf(acc);
  }
  __syncthreads();
  int r  = t >> 2;                       // 0..63 (n within tile)
  int c0 = (t & 3) * 16;                 // 0..48 (kd within tile)
  u16* dst = wt + (size_t)(n0 + r) * 4096 + kd0 + c0;
  u16x8 v0, v1;
#pragma unroll
  for (int u = 0; u < 8; ++u) { v0[u] = tile[c0 + u][r]; v1[u] = tile[c0 + 8 + u][r]; }
  *(u16x8*)dst = v0;
  *(u16x8*)(dst + 8) = v1;
}

// ---------------- fused: x -> bf16 xpad (zero-padded) AND coarse[i]=x[max(0,i-3)] ----------------
__global__ __launch_bounds__(256) void k_prep(const float* __restrict__ x,
                                              u16* __restrict__ xpad,
                                              float* __restrict__ outc) {
  int bid = blockIdx.x;
  if (bid >= 8192) {
    int z = (bid - 8192) * 256 + threadIdx.x;     // 0..4095, 8 u16 each
    u16x8 zero = {};
    if (z < 512) {
      *(u16x8*)&xpad[(size_t)z * 8] = zero;
    } else {
      size_t zz = (size_t)(z - 512);
      *(u16x8*)&xpad[(size_t)(PADR + T_LEN) * 512 + zz * 8] = zero;
    }
    return;
  }
  long t = (long)bid * 256 + threadIdx.x;
  long idx = t * 4;                                // element index into x flat
  int i = (int)(idx >> 9);
  int d = (int)(idx & 511);
  f32x4 v = *(const f32x4*)&x[idx];
  u16x4 o;
#pragma unroll
  for (int u = 0; u < 4; ++u) o[u] = f2bf(v[u]);
  *(u16x4*)&xpad[(size_t)(i + PADR) * 512 + d] = o;
  if (i <= T_LEN - 4) *(f32x4*)&outc[(size_t)(i + 3) * 512 + d] = v;
  if (i == 0) {
    *(f32x4*)&outc[(size_t)0 * 512 + d] = v;
    *(f32x4*)&outc[(size_t)1 * 512 + d] = v;
    *(f32x4*)&outc[(size_t)2 * 512 + d] = v;
  }
}

// ---------------- conv-GEMM, kc-sliced A staging ----------------
// Step (kc,s) processes K cols [s*512 + kc*64, +64).
// A[i][that chunk] = xpad[(i0+i+5+s)*512 + kc*64 + j]  -> slab[i+s][j], slab staged once per kc.
// T2 swizzle: 16B slot phys = logical ^ (row&7); gll_lds dest linear, source pre-swizzled.

__device__ __forceinline__ void stageA(const u16* __restrict__ xpad, u16* dstA,
                                       int i0, int colbase, int tid, int p) {
  int c = p * 512 + tid;                 // chunk id: row = c>>3 (0..319)
  int r = c >> 3;
  int sl = (c & 7) ^ (r & 7);
  gll16(xpad + (size_t)(i0 + 5 + r) * 512 + colbase + sl * 8, dstA + (size_t)c * 8);
}
__device__ __forceinline__ void stageB(const u16* __restrict__ wt, u16* dstB,
                                       int n0, int colbase, int tid, int p) {
  int c = p * 512 + tid;                 // row = c>>3 (0..127)
  int r = c >> 3;
  int sl = (c & 7) ^ (r & 7);
  gll16(wt + (size_t)(n0 + r) * 4096 + colbase + sl * 8, dstB + (size_t)c * 8);
}
__device__ __forceinline__ bf16x8 rdfrag(const u16* base, int row, int slot_log) {
  int sl = slot_log ^ (row & 7);
  return *(const bf16x8*)(base + row * 64 + sl * 8);
}

#define MFMA __builtin_amdgcn_mfma_f32_16x16x32_bf16

template<int NT>
__device__ __forceinline__ void vwait() {
  if constexpr (NT == 0)      asm volatile("s_waitcnt vmcnt(0)" ::: "memory");
  else if constexpr (NT == 2) asm volatile("s_waitcnt vmcnt(2)" ::: "memory");
  else if constexpr (NT == 3) asm volatile("s_waitcnt vmcnt(3)" ::: "memory");
  else if constexpr (NT == 4) asm volatile("s_waitcnt vmcnt(4)" ::: "memory");
}

// One k-step: 2 phases x {8 ds_read_b128, stage, barrier, lgkm0, 16 MFMA, barrier}
template<int S, bool APASS, bool BSTG, int NTAIL, bool DOWAIT>
__device__ __forceinline__ void gstep(const u16* __restrict__ xpad, const u16* __restrict__ wt,
                                      const u16* Ac, u16* An, u16* Bbase,
                                      int i0, int n0, int kc, int lane, int wr, int wc,
                                      int tid, f32x4 (&acc)[4][4]) {
  const u16* Br = Bbase + (size_t)(S & 3) * BELEMS;
  u16* Bw = Bbase + (size_t)((S + 2) & 3) * BELEMS;
  int slg = lane >> 4;
  int abase = wr * 64 + (lane & 15) + S;     // slab row incl. tap shift
  int bbase = wc * 64 + (lane & 15);

  // ---- phase 0 (ks = 0) ----
  {
    bf16x8 a[4], b[4];
#pragma unroll
    for (int m = 0; m < 4; ++m) a[m] = rdfrag(Ac, abase + m * 16, slg);
#pragma unroll
    for (int n = 0; n < 4; ++n) b[n] = rdfrag(Br, bbase + n * 16, slg);
    if constexpr (BSTG) {
      int colB = ((S + 2) & 7) * 512 + (kc + ((S + 2) >> 3)) * 64;
      stageB(wt, Bw, n0, colB, tid, 0);
      stageB(wt, Bw, n0, colB, tid, 1);
    }
    __builtin_amdgcn_s_barrier();
    asm volatile("s_waitcnt lgkmcnt(0)" ::: "memory");
    __builtin_amdgcn_sched_barrier(0);
    __builtin_amdgcn_s_setprio(1);
#pragma unroll
    for (int m = 0; m < 4; ++m)
#pragma unroll
      for (int n = 0; n < 4; ++n)
        acc[m][n] = MFMA(a[m], b[n], acc[m][n], 0, 0, 0);
    __builtin_amdgcn_s_setprio(0);
    __builtin_amdgcn_s_barrier();
  }
  // ---- phase 1 (ks = 1) ----
  {
    bf16x8 a[4], b[4];
#pragma unroll
    for (int m = 0; m < 4; ++m) a[m] = rdfrag(Ac, abase + m * 16, slg + 4);
#pragma unroll
    for (int n = 0; n < 4; ++n) b[n] = rdfrag(Br, bbase + n * 16, slg + 4);
    if constexpr (APASS) stageA(xpad, An, i0, (kc + 1) * 64, tid, S);  // pass S in 0..4
    __builtin_amdgcn_s_barrier();
    asm volatile("s_waitcnt lgkmcnt(0)" ::: "memory");
    __builtin_amdgcn_sched_barrier(0);
    __builtin_amdgcn_s_setprio(1);
#pragma unroll
    for (int m = 0; m < 4; ++m)
#pragma unroll
      for (int n = 0; n < 4; ++n)
        acc[m][n] = MFMA(a[m], b[n], acc[m][n], 0, 0, 0);
    __builtin_amdgcn_s_setprio(0);
    if constexpr (DOWAIT) vwait<NTAIL>();
    __builtin_amdgcn_s_barrier();
  }
}

__global__ __launch_bounds__(512, 2) void k_gemm(const u16* __restrict__ xpad,
                                                 const u16* __restrict__ wt,
                                                 const float* __restrict__ bias,
                                                 float* __restrict__ fine) {
  __shared__ __align__(16) u16 lds[2 * AELEMS + 4 * BELEMS];   // 80 + 64 = 144 KiB
  // T1: XCD-contiguous block mapping (256 % 8 == 0 -> simple bijective swizzle)
  int orig = blockIdx.x;
  int id = (orig & 7) * 32 + (orig >> 3);
  int n0 = (id & 3) * BN;
  int i0 = (id >> 2) * BM;
  int tid = threadIdx.x;
  int lane = tid & 63;
  int wid = tid >> 6;
  int wr = wid >> 1, wc = wid & 1;   // 4m x 2n wave grid; per-wave 64x64 output
  f32x4 acc[4][4] = {};

  u16* A0 = &lds[0];
  u16* A1 = &lds[AELEMS];
  u16* Bb = &lds[2 * AELEMS];

  // prologue: A slab kc=0 (5 passes) + B steps u=0 (colbase 0), u=1 (colbase 512)
#pragma unroll
  for (int p = 0; p < 5; ++p) stageA(xpad, A0, i0, 0, tid, p);
  stageB(wt, Bb, n0, 0, tid, 0);
  stageB(wt, Bb, n0, 0, tid, 1);
  stageB(wt, Bb + BELEMS, n0, 512, tid, 0);
  stageB(wt, Bb + BELEMS, n0, 512, tid, 1);
  asm volatile("s_waitcnt vmcnt(2)" ::: "memory");   // A + B0 landed; B1 in flight
  __builtin_amdgcn_s_barrier();

  u16* Ac = A0;
  u16* An = A1;
  for (int kc = 0; kc < 7; ++kc) {
    gstep<0, true,  true, 3, true>(xpad, wt, Ac, An, Bb, i0, n0, kc, lane, wr, wc, tid, acc);
    gstep<1, true,  true, 4, true>(xpad, wt, Ac, An, Bb, i0, n0, kc, lane, wr, wc, tid, acc);
    gstep<2, true,  true, 4, true>(xpad, wt, Ac, An, Bb, i0, n0, kc, lane, wr, wc, tid, acc);
    gstep<3, true,  true, 4, true>(xpad, wt, Ac, An, Bb, i0, n0, kc, lane, wr, wc, tid, acc);
    gstep<4, true,  true, 4, true>(xpad, wt, Ac, An, Bb, i0, n0, kc, lane, wr, wc, tid, acc);
    gstep<5, false, true, 3, true>(xpad, wt, Ac, An, Bb, i0, n0, kc, lane, wr, wc, tid, acc);
    gstep<6, false, true, 2, true>(xpad, wt, Ac, An, Bb, i0, n0, kc, lane, wr, wc, tid, acc);
    gstep<7, false, true, 2, true>(xpad, wt, Ac, An, Bb, i0, n0, kc, lane, wr, wc, tid, acc);
    u16* tmp = Ac; Ac = An; An = tmp;
  }
  // kc = 7 epilogue (no A pass; B staging ends at s=5)
  gstep<0, false, true,  2, true >(xpad, wt, Ac, An, Bb, i0, n0, 7, lane, wr, wc, tid, acc);
  gstep<1, false, true,  2, true >(xpad, wt, Ac, An, Bb, i0, n0, 7, lane, wr, wc, tid, acc);
  gstep<2, false, true,  2, true >(xpad, wt, Ac, An, Bb, i0, n0, 7, lane, wr, wc, tid, acc);
  gstep<3, false, true,  2, true >(xpad, wt, Ac, An, Bb, i0, n0, 7, lane, wr, wc, tid, acc);
  gstep<4, false, true,  2, true >(xpad, wt, Ac, An, Bb, i0, n0, 7, lane, wr, wc, tid, acc);
  gstep<5, false, true,  2, true >(xpad, wt, Ac, An, Bb, i0, n0, 7, lane, wr, wc, tid, acc);
  gstep<6, false, false, 0, true >(xpad, wt, Ac, An, Bb, i0, n0, 7, lane, wr, wc, tid, acc);
  gstep<7, false, false, 0, false>(xpad, wt, Ac, An, Bb, i0, n0, 7, lane, wr, wc, tid, acc);

  // epilogue: bias + exact GELU
#pragma unroll
  for (int n = 0; n < 4; ++n) {
    int col = n0 + wc * 64 + n * 16 + (lane & 15);
    float bv = bias[col];
#pragma unroll
    for (int m = 0; m < 4; ++m) {
      int row = i0 + wr * 64 + m * 16 + ((lane >> 4) * 4);
      f32x4 v = acc[m][n];
#pragma unroll
      for (int e = 0; e < 4; ++e)
        fine[(size_t)(row + e) * 512 + col] = gelu_exact(v[e] + bv);
    }
  }
}

// ---------------- left-edge fixup: one wave per (i,n), coalesced + butterfly reduce ----------------
__global__ __launch_bounds__(256) void k_edge(const u16* __restrict__ xpad, const u16* __restrict__ wt,
                                              const float* __restrict__ bias, float* __restrict__ fine) {
  int o = blockIdx.x * 4 + (threadIdx.x >> 6);   // 0..1535 output id
  int lane = threadIdx.x & 63;
  int i = o >> 9;            // 0..2
  int n = o & 511;
  int len = (i + 5) * 512;   // window covers x[0..i+4]
  const u16* xr = xpad + PADR * 512;
  const u16* wrow = wt + (size_t)n * 4096;
  float s = 0.f;
#pragma unroll
  for (int m = 0; m < 7; ++m) {
    int k = (m * 64 + lane) * 8;
    if (k < len) {
      u16x8 xv = *(const u16x8*)&xr[k];
      u16x8 wv = *(const u16x8*)&wrow[k];
#pragma unroll
      for (int u = 0; u < 8; ++u) s += bf2f(xv[u]) * bf2f(wv[u]);
    }
  }
#pragma unroll
  for (int off = 32; off; off >>= 1) s += __shfl_xor(s, off);
  if (lane == 0) fine[(size_t)i * 512 + n] = gelu_exact(s + bias[n]);
}

extern "C" void kernel_launch(void* const* d_in, const int* in_sizes, int n_in,
                              void* d_out, int out_size, void* d_ws, size_t ws_size,
                              hipStream_t stream) {
  const float* x = (const float*)d_in[0];    // [1,16384,512]
  const float* W = (const float*)d_in[1];    // [4096,512]
  const float* b = (const float*)d_in[2];    // [512]
  float* outc = (float*)d_out;                         // coarse [16384,512]
  float* outf = (float*)d_out + (size_t)T_LEN * DDIM;  // fine   [16384,512]

  u16* xpad = (u16*)d_ws;                                        // XROWS*512*2 = 16,842,752 B
  u16* wt   = (u16*)((char*)d_ws + (size_t)XROWS * 512 * 2);     // 512*4096*2  =  4,194,304 B

  k_fold <<<dim3(64, 8),   256, 0, stream>>>(W, wt);
  k_prep <<<dim3(8208),    256, 0, stream>>>(x, xpad, outc);
  k_gemm <<<dim3(256),     512, 0, stream>>>(xpad, wt, b, outf);
  k_edge <<<dim3(384),     256, 0, stream>>>(xpad, wt, b, outf);
}